// Round 1
// baseline (1545.493 us; speedup 1.0000x reference)
//
#include <hip/hip_runtime.h>
#include <math.h>

#define IN_DIM 256
#define OUT_DIM 128
#define NH 8
#define HD 16
#define GH 16
#define TBL 4096

// ---------------- geo bias table: bias(dist) per head, 4096-point lerp table ----------------
__global__ void geo_table_kernel(const float* __restrict__ Wg1, const float* __restrict__ bg1,
                                 const float* __restrict__ Wg2, const float* __restrict__ bg2,
                                 float* __restrict__ tbl) {
    int i = blockIdx.x * blockDim.x + threadIdx.x;
    if (i >= TBL) return;
    float d = (float)i * (6.0f / (float)(TBL - 1));
    float rbf[GH];
#pragma unroll
    for (int j = 0; j < GH; ++j) {
        float c = 0.4f * (float)j;           // linspace(0,6,16) step = 0.4
        float t = d - c;
        rbf[j] = __expf(-t * t);
    }
    float hid[GH];
#pragma unroll
    for (int j = 0; j < GH; ++j) {
        float acc = bg1[j];
#pragma unroll
        for (int kk = 0; kk < GH; ++kk) acc += rbf[kk] * Wg1[j * GH + kk];
        hid[j] = fmaxf(acc, 0.0f);
    }
#pragma unroll
    for (int h = 0; h < NH; ++h) {
        float acc = bg2[h];
#pragma unroll
        for (int j = 0; j < GH; ++j) acc += hid[j] * Wg2[h * GH + j];
        tbl[i * NH + h] = acc;
    }
}

// ---------------- fp32 register-tiled GEMM: out[n][f] = in[n][:K] . W[f][:K] + b[f] ----------------
// 64 nodes x 128 features per block, 256 threads, thread tile 4x8, K-chunks of 32.
template <int K>
static __device__ __forceinline__ void gemm_tile(const float* __restrict__ X,
                                                 const float* __restrict__ W,
                                                 const float* __restrict__ b,
                                                 float* __restrict__ out,
                                                 int n0, int Nn) {
    __shared__ float xs[64 * 36];    // stride 36 (pad) keeps float4 alignment + spreads banks
    __shared__ float wsm[128 * 36];
    const int tid = threadIdx.x;
    const int tx = tid & 15;        // feature group: features tx*8 .. tx*8+7
    const int ty = tid >> 4;        // node group:    nodes   ty*4 .. ty*4+3
    float acc[4][8];
#pragma unroll
    for (int i = 0; i < 4; ++i)
#pragma unroll
        for (int j = 0; j < 8; ++j) acc[i][j] = 0.0f;

    const int rows_valid = min(64, Nn - n0);

    for (int kc = 0; kc < K; kc += 32) {
        // stage x tile [64][32]
#pragma unroll
        for (int l = 0; l < 2; ++l) {
            int fl = tid + l * 256;          // 0..511 -> (row, col4)
            int r = fl >> 3, c4 = fl & 7;
            float4 val = make_float4(0.f, 0.f, 0.f, 0.f);
            if (r < rows_valid) val = *(const float4*)(X + (size_t)(n0 + r) * K + kc + c4 * 4);
            *(float4*)(xs + r * 36 + c4 * 4) = val;
        }
        // stage W tile [128][32]
#pragma unroll
        for (int l = 0; l < 4; ++l) {
            int fl = tid + l * 256;          // 0..1023
            int r = fl >> 3, c4 = fl & 7;
            float4 val = *(const float4*)(W + (size_t)r * K + kc + c4 * 4);
            *(float4*)(wsm + r * 36 + c4 * 4) = val;
        }
        __syncthreads();
#pragma unroll
        for (int k4 = 0; k4 < 8; ++k4) {
            float4 xa[4], wb[8];
#pragma unroll
            for (int i = 0; i < 4; ++i) xa[i] = *(const float4*)(xs + (ty * 4 + i) * 36 + k4 * 4);
#pragma unroll
            for (int j = 0; j < 8; ++j) wb[j] = *(const float4*)(wsm + (tx * 8 + j) * 36 + k4 * 4);
#pragma unroll
            for (int i = 0; i < 4; ++i)
#pragma unroll
                for (int j = 0; j < 8; ++j) {
                    acc[i][j] += xa[i].x * wb[j].x;
                    acc[i][j] += xa[i].y * wb[j].y;
                    acc[i][j] += xa[i].z * wb[j].z;
                    acc[i][j] += xa[i].w * wb[j].w;
                }
        }
        __syncthreads();
    }

    float bj[8];
#pragma unroll
    for (int j = 0; j < 8; ++j) bj[j] = b[tx * 8 + j];
#pragma unroll
    for (int i = 0; i < 4; ++i) {
        int r = ty * 4 + i;
        if (r < rows_valid) {
            float4 o0 = make_float4(acc[i][0] + bj[0], acc[i][1] + bj[1],
                                    acc[i][2] + bj[2], acc[i][3] + bj[3]);
            float4 o1 = make_float4(acc[i][4] + bj[4], acc[i][5] + bj[5],
                                    acc[i][6] + bj[6], acc[i][7] + bj[7]);
            float* op = out + (size_t)(n0 + r) * 128 + tx * 8;
            *(float4*)op = o0;
            *(float4*)(op + 4) = o1;
        }
    }
}

__global__ __launch_bounds__(256) void qkv_kernel(const float* __restrict__ x,
                                                  const float* __restrict__ Wq, const float* __restrict__ bq,
                                                  const float* __restrict__ Wk, const float* __restrict__ bk,
                                                  const float* __restrict__ Wv, const float* __restrict__ bv,
                                                  float* __restrict__ q, float* __restrict__ k,
                                                  float* __restrict__ v, int Nn) {
    int n0 = blockIdx.x * 64;
    int w = blockIdx.y;
    const float* W = (w == 0) ? Wq : (w == 1) ? Wk : Wv;
    const float* b = (w == 0) ? bq : (w == 1) ? bk : bv;
    float* out = (w == 0) ? q : (w == 1) ? k : v;
    gemm_tile<IN_DIM>(x, W, b, out, n0, Nn);
}

__global__ __launch_bounds__(256) void out_gemm_kernel(const float* __restrict__ in,
                                                       const float* __restrict__ Wo, const float* __restrict__ bo,
                                                       float* __restrict__ out, int Nn) {
    gemm_tile<OUT_DIM>(in, Wo, bo, out, blockIdx.x * 64, Nn);
}

// ---------------- CSR build ----------------
__global__ void deg_kernel(const int* __restrict__ ei, int* __restrict__ deg, int E_) {
    int e = blockIdx.x * 256 + threadIdx.x;
    if (e < E_) atomicAdd(&deg[ei[e]], 1);
}

__global__ __launch_bounds__(1024) void scan_kernel(const int* __restrict__ deg,
                                                    int* __restrict__ rowstart,
                                                    int* __restrict__ cursor, int n) {
    __shared__ int sm[1024];
    int t = threadIdx.x;
    int chunk = (n + 1023) / 1024;
    int b0 = t * chunk;
    int b1 = min(b0 + chunk, n);
    int lsum = 0;
    for (int i = b0; i < b1; ++i) lsum += deg[i];
    sm[t] = lsum;
    __syncthreads();
    for (int off = 1; off < 1024; off <<= 1) {
        int other = (t >= off) ? sm[t - off] : 0;
        __syncthreads();
        sm[t] += other;
        __syncthreads();
    }
    int run = sm[t] - lsum;  // exclusive prefix
    for (int i = b0; i < b1; ++i) {
        rowstart[i] = run;
        cursor[i] = run;
        run += deg[i];
    }
    if (t == 1023) rowstart[n] = sm[1023];
}

// ---------------- edge pass: attn = qk dot * scale + geo_bias, scattered into CSR order ----------------
// 8 lanes per edge (one per head), 32 edges per 256-thread block.
__global__ __launch_bounds__(256) void edge_kernel(const int* __restrict__ ei,
                                                   const float* __restrict__ edist,
                                                   const float* __restrict__ q,
                                                   const float* __restrict__ k,
                                                   const float* __restrict__ tbl,
                                                   int* __restrict__ cursor,
                                                   float* __restrict__ attn,
                                                   int* __restrict__ ccol, int E_) {
    int tid = threadIdx.x;
    int g = tid >> 3, h = tid & 7;
    int e = blockIdx.x * 32 + g;
    if (e >= E_) return;
    int row = ei[e];
    int col = ei[E_ + e];
    float dist = edist[e];

    // geo bias via table lerp
    float u = dist * ((float)(TBL - 1) / 6.0f);
    u = fminf(fmaxf(u, 0.0f), (float)(TBL - 1));
    int i0 = (int)u;
    if (i0 > TBL - 2) i0 = TBL - 2;
    float fr = u - (float)i0;
    float t0 = tbl[i0 * NH + h];
    float t1 = tbl[(i0 + 1) * NH + h];
    float bias = t0 + fr * (t1 - t0);

    const float4* qp = (const float4*)(q + (size_t)row * 128 + h * 16);
    const float4* kp = (const float4*)(k + (size_t)col * 128 + h * 16);
    float dot = 0.0f;
#pragma unroll
    for (int i = 0; i < 4; ++i) {
        float4 a = qp[i];
        float4 bb = kp[i];
        dot += a.x * bb.x + a.y * bb.y + a.z * bb.z + a.w * bb.w;
    }
    float attn_v = dot * 0.25f + bias;   // scale = 1/sqrt(16)

    int pos = 0;
    if (h == 0) pos = atomicAdd(&cursor[row], 1);
    int lane = tid & 63;
    pos = __shfl(pos, lane & ~7, 64);    // broadcast from lane h==0 of this 8-lane group

    attn[(size_t)pos * 8 + h] = attn_v;
    if (h == 0) ccol[pos] = col;
}

// ---------------- node pass: exact segment softmax + v aggregation, one wave per node ----------------
__global__ __launch_bounds__(256) void node_kernel(const float* __restrict__ attn,
                                                   const int* __restrict__ ccol,
                                                   const float* __restrict__ v,
                                                   const int* __restrict__ rowstart,
                                                   float* __restrict__ outacc, int Nn) {
    int lane = threadIdx.x & 63;
    int n = blockIdx.x * 4 + (threadIdx.x >> 6);
    if (n >= Nn) return;
    int start = rowstart[n];
    int end = rowstart[n + 1];

    float m[NH], s[NH];
#pragma unroll
    for (int h = 0; h < NH; ++h) { m[h] = -1e30f; s[h] = 0.0f; }

    // phase 1: online (m, s) per head, lanes stride over edges
    for (int i = start + lane; i < end; i += 64) {
        float4 a0 = *(const float4*)(attn + (size_t)i * 8);
        float4 a1 = *(const float4*)(attn + (size_t)i * 8 + 4);
        float av[8] = {a0.x, a0.y, a0.z, a0.w, a1.x, a1.y, a1.z, a1.w};
#pragma unroll
        for (int h = 0; h < NH; ++h) {
            float nm = fmaxf(m[h], av[h]);
            s[h] = s[h] * __expf(m[h] - nm) + __expf(av[h] - nm);
            m[h] = nm;
        }
    }
    // cross-lane combine (sentinel -1e30 keeps exp(0)=1 path NaN-free)
#pragma unroll
    for (int off = 1; off < 64; off <<= 1) {
#pragma unroll
        for (int h = 0; h < NH; ++h) {
            float om = __shfl_xor(m[h], off);
            float os = __shfl_xor(s[h], off);
            float nm = fmaxf(m[h], om);
            s[h] = s[h] * __expf(m[h] - nm) + os * __expf(om - nm);
            m[h] = nm;
        }
    }

    int h0 = lane >> 4;  // lane covers features f=lane (head h0) and f=lane+64 (head h0+4)
    float m0 = (h0 == 0) ? m[0] : (h0 == 1) ? m[1] : (h0 == 2) ? m[2] : m[3];
    float s0 = (h0 == 0) ? s[0] : (h0 == 1) ? s[1] : (h0 == 2) ? s[2] : s[3];
    float m1 = (h0 == 0) ? m[4] : (h0 == 1) ? m[5] : (h0 == 2) ? m[6] : m[7];
    float s1 = (h0 == 0) ? s[4] : (h0 == 1) ? s[5] : (h0 == 2) ? s[6] : s[7];
    float is0 = 1.0f / (s0 + 1e-12f);
    float is1 = 1.0f / (s1 + 1e-12f);

    float acc0 = 0.0f, acc1 = 0.0f;
    for (int i = start; i < end; ++i) {
        int col = ccol[i];
        float a0 = attn[(size_t)i * 8 + h0];
        float a1 = attn[(size_t)i * 8 + 4 + h0];
        float w0 = __expf(a0 - m0) * is0;
        float w1 = __expf(a1 - m1) * is1;
        const float* vp = v + (size_t)col * 128;
        acc0 += w0 * vp[lane];
        acc1 += w1 * vp[64 + lane];
    }
    float* op = outacc + (size_t)n * 128;
    op[lane] = acc0;
    op[64 + lane] = acc1;
}

extern "C" void kernel_launch(void* const* d_in, const int* in_sizes, int n_in,
                              void* d_out, int out_size, void* d_ws, size_t ws_size,
                              hipStream_t stream) {
    const float* x   = (const float*)d_in[0];
    const int* ei    = (const int*)d_in[1];
    const float* edist = (const float*)d_in[2];
    const float* Wq = (const float*)d_in[3];  const float* bq = (const float*)d_in[4];
    const float* Wk = (const float*)d_in[5];  const float* bk = (const float*)d_in[6];
    const float* Wv = (const float*)d_in[7];  const float* bv = (const float*)d_in[8];
    const float* Wo = (const float*)d_in[9];  const float* bo = (const float*)d_in[10];
    const float* Wg1 = (const float*)d_in[11]; const float* bg1 = (const float*)d_in[12];
    const float* Wg2 = (const float*)d_in[13]; const float* bg2 = (const float*)d_in[14];
    const int Nn = in_sizes[0] / IN_DIM;
    const int Ee = in_sizes[2];
    float* out = (float*)d_out;

    char* ws = (char*)d_ws;
    size_t off = 0;
    auto alloc = [&](size_t bytes) -> char* {
        char* p = ws + off;
        off += (bytes + 255) & ~(size_t)255;
        return p;
    };
    float* q    = (float*)alloc((size_t)Nn * 128 * 4);
    float* kbuf = (float*)alloc((size_t)Nn * 128 * 4);
    float* vbuf = (float*)alloc((size_t)Nn * 128 * 4);
    float* attn = (float*)alloc((size_t)Ee * 8 * 4);
    float* geot = (float*)alloc((size_t)TBL * 8 * 4);
    int* ccol     = (int*)alloc((size_t)Ee * 4);
    int* deg      = (int*)alloc((size_t)Nn * 4);
    int* rowstart = (int*)alloc((size_t)(Nn + 1) * 4);
    int* cursor   = (int*)alloc((size_t)Nn * 4);
    float* outacc = q;  // q is dead after edge_kernel; reuse as aggregation output

    hipMemsetAsync(deg, 0, (size_t)Nn * 4, stream);

    geo_table_kernel<<<(TBL + 255) / 256, 256, 0, stream>>>(Wg1, bg1, Wg2, bg2, geot);

    dim3 gq((Nn + 63) / 64, 3);
    qkv_kernel<<<gq, 256, 0, stream>>>(x, Wq, bq, Wk, bk, Wv, bv, q, kbuf, vbuf, Nn);

    deg_kernel<<<(Ee + 255) / 256, 256, 0, stream>>>(ei, deg, Ee);
    scan_kernel<<<1, 1024, 0, stream>>>(deg, rowstart, cursor, Nn);

    edge_kernel<<<(Ee + 31) / 32, 256, 0, stream>>>(ei, edist, q, kbuf, geot, cursor, attn, ccol, Ee);

    node_kernel<<<(Nn + 3) / 4, 256, 0, stream>>>(attn, ccol, vbuf, rowstart, outacc, Nn);

    out_gemm_kernel<<<(Nn + 63) / 64, 256, 0, stream>>>(outacc, Wo, bo, out, Nn);
}

// Round 2
// 689.696 us; speedup vs baseline: 2.2408x; 2.2408x over previous
//
#include <hip/hip_runtime.h>
#include <math.h>

#define IN_DIM 256
#define OUT_DIM 128
#define NH 8
#define HD 16
#define GH 16
#define TBL 4096

// ---------------- geo bias table: bias(dist) per head, 4096-point lerp table ----------------
__global__ void geo_table_kernel(const float* __restrict__ Wg1, const float* __restrict__ bg1,
                                 const float* __restrict__ Wg2, const float* __restrict__ bg2,
                                 float* __restrict__ tbl) {
    int i = blockIdx.x * blockDim.x + threadIdx.x;
    if (i >= TBL) return;
    float d = (float)i * (6.0f / (float)(TBL - 1));
    float rbf[GH];
#pragma unroll
    for (int j = 0; j < GH; ++j) {
        float c = 0.4f * (float)j;           // linspace(0,6,16) step = 0.4
        float t = d - c;
        rbf[j] = __expf(-t * t);
    }
    float hid[GH];
#pragma unroll
    for (int j = 0; j < GH; ++j) {
        float acc = bg1[j];
#pragma unroll
        for (int kk = 0; kk < GH; ++kk) acc += rbf[kk] * Wg1[j * GH + kk];
        hid[j] = fmaxf(acc, 0.0f);
    }
#pragma unroll
    for (int h = 0; h < NH; ++h) {
        float acc = bg2[h];
#pragma unroll
        for (int j = 0; j < GH; ++j) acc += hid[j] * Wg2[h * GH + j];
        tbl[i * NH + h] = acc;
    }
}

// ---------------- fp32 register-tiled GEMM: out[n][f] = in[n][:K] . W[f][:K] + b[f] ----------------
// 64 nodes x 128 features per block, 256 threads, thread tile 4x8, K-chunks of 32.
// LDS tiles use stride 32 + XOR slot swizzle (slot = c4 ^ ((row>>3)&7)) so that the
// 16 tx-groups (rows 8 apart) spread across all 8 float4-slot bank groups: 2-way
// aliasing max, which is free on CDNA4 (m136). Pad-36 layout was 16-way conflicted
// (8*36 == 0 mod 32) -> 4.25e8 conflict cycles = 692us measured in R1.
template <int K>
static __device__ __forceinline__ void gemm_tile(const float* __restrict__ X,
                                                 const float* __restrict__ W,
                                                 const float* __restrict__ b,
                                                 float* __restrict__ out,
                                                 int n0, int Nn) {
    __shared__ float xs[64 * 32];
    __shared__ float wsm[128 * 32];
    const int tid = threadIdx.x;
    const int tx = tid & 15;        // feature group: features tx*8 .. tx*8+7
    const int ty = tid >> 4;        // node group:    nodes   ty*4 .. ty*4+3
    float acc[4][8];
#pragma unroll
    for (int i = 0; i < 4; ++i)
#pragma unroll
        for (int j = 0; j < 8; ++j) acc[i][j] = 0.0f;

    const int rows_valid = min(64, Nn - n0);

    for (int kc = 0; kc < K; kc += 32) {
        // stage x tile [64][32]
#pragma unroll
        for (int l = 0; l < 2; ++l) {
            int fl = tid + l * 256;          // 0..511 -> (row, col4)
            int r = fl >> 3, c4 = fl & 7;
            float4 val = make_float4(0.f, 0.f, 0.f, 0.f);
            if (r < rows_valid) val = *(const float4*)(X + (size_t)(n0 + r) * K + kc + c4 * 4);
            int slot = c4 ^ ((r >> 3) & 7);
            *(float4*)(xs + r * 32 + slot * 4) = val;
        }
        // stage W tile [128][32]
#pragma unroll
        for (int l = 0; l < 4; ++l) {
            int fl = tid + l * 256;          // 0..1023
            int r = fl >> 3, c4 = fl & 7;
            float4 val = *(const float4*)(W + (size_t)r * K + kc + c4 * 4);
            int slot = c4 ^ ((r >> 3) & 7);
            *(float4*)(wsm + r * 32 + slot * 4) = val;
        }
        __syncthreads();
#pragma unroll
        for (int k4 = 0; k4 < 8; ++k4) {
            float4 xa[4], wb[8];
#pragma unroll
            for (int i = 0; i < 4; ++i) {
                int r = ty * 4 + i;
                int slot = k4 ^ ((r >> 3) & 7);
                xa[i] = *(const float4*)(xs + r * 32 + slot * 4);
            }
#pragma unroll
            for (int j = 0; j < 8; ++j) {
                int r = tx * 8 + j;
                int slot = k4 ^ ((r >> 3) & 7);
                wb[j] = *(const float4*)(wsm + r * 32 + slot * 4);
            }
#pragma unroll
            for (int i = 0; i < 4; ++i)
#pragma unroll
                for (int j = 0; j < 8; ++j) {
                    acc[i][j] += xa[i].x * wb[j].x;
                    acc[i][j] += xa[i].y * wb[j].y;
                    acc[i][j] += xa[i].z * wb[j].z;
                    acc[i][j] += xa[i].w * wb[j].w;
                }
        }
        __syncthreads();
    }

    float bj[8];
#pragma unroll
    for (int j = 0; j < 8; ++j) bj[j] = b[tx * 8 + j];
#pragma unroll
    for (int i = 0; i < 4; ++i) {
        int r = ty * 4 + i;
        if (r < rows_valid) {
            float4 o0 = make_float4(acc[i][0] + bj[0], acc[i][1] + bj[1],
                                    acc[i][2] + bj[2], acc[i][3] + bj[3]);
            float4 o1 = make_float4(acc[i][4] + bj[4], acc[i][5] + bj[5],
                                    acc[i][6] + bj[6], acc[i][7] + bj[7]);
            float* op = out + (size_t)(n0 + r) * 128 + tx * 8;
            *(float4*)op = o0;
            *(float4*)(op + 4) = o1;
        }
    }
}

__global__ __launch_bounds__(256) void qkv_kernel(const float* __restrict__ x,
                                                  const float* __restrict__ Wq, const float* __restrict__ bq,
                                                  const float* __restrict__ Wk, const float* __restrict__ bk,
                                                  const float* __restrict__ Wv, const float* __restrict__ bv,
                                                  float* __restrict__ q, float* __restrict__ k,
                                                  float* __restrict__ v, int Nn) {
    int n0 = blockIdx.x * 64;
    int w = blockIdx.y;
    const float* W = (w == 0) ? Wq : (w == 1) ? Wk : Wv;
    const float* b = (w == 0) ? bq : (w == 1) ? bk : bv;
    float* out = (w == 0) ? q : (w == 1) ? k : v;
    gemm_tile<IN_DIM>(x, W, b, out, n0, Nn);
}

__global__ __launch_bounds__(256) void out_gemm_kernel(const float* __restrict__ in,
                                                       const float* __restrict__ Wo, const float* __restrict__ bo,
                                                       float* __restrict__ out, int Nn) {
    gemm_tile<OUT_DIM>(in, Wo, bo, out, blockIdx.x * 64, Nn);
}

// ---------------- CSR build ----------------
__global__ void deg_kernel(const int* __restrict__ ei, int* __restrict__ deg, int E_) {
    int e = blockIdx.x * 256 + threadIdx.x;
    if (e < E_) atomicAdd(&deg[ei[e]], 1);
}

__global__ __launch_bounds__(1024) void scan_kernel(const int* __restrict__ deg,
                                                    int* __restrict__ rowstart,
                                                    int* __restrict__ cursor, int n) {
    __shared__ int sm[1024];
    int t = threadIdx.x;
    int chunk = (n + 1023) / 1024;
    int b0 = t * chunk;
    int b1 = min(b0 + chunk, n);
    int lsum = 0;
    for (int i = b0; i < b1; ++i) lsum += deg[i];
    sm[t] = lsum;
    __syncthreads();
    for (int off = 1; off < 1024; off <<= 1) {
        int other = (t >= off) ? sm[t - off] : 0;
        __syncthreads();
        sm[t] += other;
        __syncthreads();
    }
    int run = sm[t] - lsum;  // exclusive prefix
    for (int i = b0; i < b1; ++i) {
        rowstart[i] = run;
        cursor[i] = run;
        run += deg[i];
    }
    if (t == 1023) rowstart[n] = sm[1023];
}

// ---------------- edge pass: attn = qk dot * scale + geo_bias, scattered into CSR order ----------------
// 8 lanes per edge (one per head), 32 edges per 256-thread block.
__global__ __launch_bounds__(256) void edge_kernel(const int* __restrict__ ei,
                                                   const float* __restrict__ edist,
                                                   const float* __restrict__ q,
                                                   const float* __restrict__ k,
                                                   const float* __restrict__ tbl,
                                                   int* __restrict__ cursor,
                                                   float* __restrict__ attn,
                                                   int* __restrict__ ccol, int E_) {
    int tid = threadIdx.x;
    int g = tid >> 3, h = tid & 7;
    int e = blockIdx.x * 32 + g;
    if (e >= E_) return;
    int row = ei[e];
    int col = ei[E_ + e];
    float dist = edist[e];

    // geo bias via table lerp
    float u = dist * ((float)(TBL - 1) / 6.0f);
    u = fminf(fmaxf(u, 0.0f), (float)(TBL - 1));
    int i0 = (int)u;
    if (i0 > TBL - 2) i0 = TBL - 2;
    float fr = u - (float)i0;
    float t0 = tbl[i0 * NH + h];
    float t1 = tbl[(i0 + 1) * NH + h];
    float bias = t0 + fr * (t1 - t0);

    const float4* qp = (const float4*)(q + (size_t)row * 128 + h * 16);
    const float4* kp = (const float4*)(k + (size_t)col * 128 + h * 16);
    float dot = 0.0f;
#pragma unroll
    for (int i = 0; i < 4; ++i) {
        float4 a = qp[i];
        float4 bb = kp[i];
        dot += a.x * bb.x + a.y * bb.y + a.z * bb.z + a.w * bb.w;
    }
    float attn_v = dot * 0.25f + bias;   // scale = 1/sqrt(16)

    int pos = 0;
    if (h == 0) pos = atomicAdd(&cursor[row], 1);
    int lane = tid & 63;
    pos = __shfl(pos, lane & ~7, 64);    // broadcast from lane h==0 of this 8-lane group

    attn[(size_t)pos * 8 + h] = attn_v;
    if (h == 0) ccol[pos] = col;
}

// ---------------- node pass: exact segment softmax + v aggregation, one wave per node ----------------
__global__ __launch_bounds__(256) void node_kernel(const float* __restrict__ attn,
                                                   const int* __restrict__ ccol,
                                                   const float* __restrict__ v,
                                                   const int* __restrict__ rowstart,
                                                   float* __restrict__ outacc, int Nn) {
    int lane = threadIdx.x & 63;
    int n = blockIdx.x * 4 + (threadIdx.x >> 6);
    if (n >= Nn) return;
    int start = rowstart[n];
    int end = rowstart[n + 1];

    float m[NH], s[NH];
#pragma unroll
    for (int h = 0; h < NH; ++h) { m[h] = -1e30f; s[h] = 0.0f; }

    // phase 1: online (m, s) per head, lanes stride over edges
    for (int i = start + lane; i < end; i += 64) {
        float4 a0 = *(const float4*)(attn + (size_t)i * 8);
        float4 a1 = *(const float4*)(attn + (size_t)i * 8 + 4);
        float av[8] = {a0.x, a0.y, a0.z, a0.w, a1.x, a1.y, a1.z, a1.w};
#pragma unroll
        for (int h = 0; h < NH; ++h) {
            float nm = fmaxf(m[h], av[h]);
            s[h] = s[h] * __expf(m[h] - nm) + __expf(av[h] - nm);
            m[h] = nm;
        }
    }
    // cross-lane combine (sentinel -1e30 keeps exp(0)=1 path NaN-free)
#pragma unroll
    for (int off = 1; off < 64; off <<= 1) {
#pragma unroll
        for (int h = 0; h < NH; ++h) {
            float om = __shfl_xor(m[h], off);
            float os = __shfl_xor(s[h], off);
            float nm = fmaxf(m[h], om);
            s[h] = s[h] * __expf(m[h] - nm) + os * __expf(om - nm);
            m[h] = nm;
        }
    }

    int h0 = lane >> 4;  // lane covers features f=lane (head h0) and f=lane+64 (head h0+4)
    float m0 = (h0 == 0) ? m[0] : (h0 == 1) ? m[1] : (h0 == 2) ? m[2] : m[3];
    float s0 = (h0 == 0) ? s[0] : (h0 == 1) ? s[1] : (h0 == 2) ? s[2] : s[3];
    float m1 = (h0 == 0) ? m[4] : (h0 == 1) ? m[5] : (h0 == 2) ? m[6] : m[7];
    float s1 = (h0 == 0) ? s[4] : (h0 == 1) ? s[5] : (h0 == 2) ? s[6] : s[7];
    float is0 = 1.0f / (s0 + 1e-12f);
    float is1 = 1.0f / (s1 + 1e-12f);

    float acc0 = 0.0f, acc1 = 0.0f;
    for (int i = start; i < end; ++i) {
        int col = ccol[i];
        float a0 = attn[(size_t)i * 8 + h0];
        float a1 = attn[(size_t)i * 8 + 4 + h0];
        float w0 = __expf(a0 - m0) * is0;
        float w1 = __expf(a1 - m1) * is1;
        const float* vp = v + (size_t)col * 128;
        acc0 += w0 * vp[lane];
        acc1 += w1 * vp[64 + lane];
    }
    float* op = outacc + (size_t)n * 128;
    op[lane] = acc0;
    op[64 + lane] = acc1;
}

extern "C" void kernel_launch(void* const* d_in, const int* in_sizes, int n_in,
                              void* d_out, int out_size, void* d_ws, size_t ws_size,
                              hipStream_t stream) {
    const float* x   = (const float*)d_in[0];
    const int* ei    = (const int*)d_in[1];
    const float* edist = (const float*)d_in[2];
    const float* Wq = (const float*)d_in[3];  const float* bq = (const float*)d_in[4];
    const float* Wk = (const float*)d_in[5];  const float* bk = (const float*)d_in[6];
    const float* Wv = (const float*)d_in[7];  const float* bv = (const float*)d_in[8];
    const float* Wo = (const float*)d_in[9];  const float* bo = (const float*)d_in[10];
    const float* Wg1 = (const float*)d_in[11]; const float* bg1 = (const float*)d_in[12];
    const float* Wg2 = (const float*)d_in[13]; const float* bg2 = (const float*)d_in[14];
    const int Nn = in_sizes[0] / IN_DIM;
    const int Ee = in_sizes[2];
    float* out = (float*)d_out;

    char* ws = (char*)d_ws;
    size_t off = 0;
    auto alloc = [&](size_t bytes) -> char* {
        char* p = ws + off;
        off += (bytes + 255) & ~(size_t)255;
        return p;
    };
    float* q    = (float*)alloc((size_t)Nn * 128 * 4);
    float* kbuf = (float*)alloc((size_t)Nn * 128 * 4);
    float* vbuf = (float*)alloc((size_t)Nn * 128 * 4);
    float* attn = (float*)alloc((size_t)Ee * 8 * 4);
    float* geot = (float*)alloc((size_t)TBL * 8 * 4);
    int* ccol     = (int*)alloc((size_t)Ee * 4);
    int* deg      = (int*)alloc((size_t)Nn * 4);
    int* rowstart = (int*)alloc((size_t)(Nn + 1) * 4);
    int* cursor   = (int*)alloc((size_t)Nn * 4);
    float* outacc = q;  // q is dead after edge_kernel; reuse as aggregation output

    hipMemsetAsync(deg, 0, (size_t)Nn * 4, stream);

    geo_table_kernel<<<(TBL + 255) / 256, 256, 0, stream>>>(Wg1, bg1, Wg2, bg2, geot);

    dim3 gq((Nn + 63) / 64, 3);
    qkv_kernel<<<gq, 256, 0, stream>>>(x, Wq, bq, Wk, bk, Wv, bv, q, kbuf, vbuf, Nn);

    deg_kernel<<<(Ee + 255) / 256, 256, 0, stream>>>(ei, deg, Ee);
    scan_kernel<<<1, 1024, 0, stream>>>(deg, rowstart, cursor, Nn);

    edge_kernel<<<(Ee + 31) / 32, 256, 0, stream>>>(ei, edist, q, kbuf, geot, cursor, attn, ccol, Ee);

    node_kernel<<<(Nn + 3) / 4, 256, 0, stream>>>(attn, ccol, vbuf, rowstart, outacc, Nn);

    out_gemm_kernel<<<(Nn + 63) / 64, 256, 0, stream>>>(outacc, Wo, bo, out, Nn);
}